// Round 10
// baseline (202.360 us; speedup 1.0000x reference)
//
#include <hip/hip_runtime.h>
#include <math.h>

#define L 2048
#define B 8
#define D 1024
#define ND 16
#define BD (B*D)
#define CK 64                // chunk length
#define NC (L/CK)            // 32 chunks

typedef float v2f __attribute__((ext_vector_type(2)));

__device__ __forceinline__ float sigmoid_precise(float v) {
    return 1.0f / (1.0f + expf(-v));
}
// fast sigmoid: v_exp + v_rcp (~3e-7 rel err; tolerance is 0.0625 abs)
__device__ __forceinline__ float sigmoid_fast(float v) {
    return __builtin_amdgcn_rcpf(1.0f + __expf(-v));
}

// Channel-packed decay for rows r0,r0+1: q2[k] = {q(ch0,mode k), q(ch1,mode k)}.
__device__ __forceinline__ void load_q2p(const float* __restrict__ damp,
                                         const float* __restrict__ decay,
                                         int r0, v2f* q2) {
#pragma unroll
    for (int mg = 0; mg < 4; ++mg) {
        const float4 dpa = reinterpret_cast<const float4*>(damp)[r0 * 4 + mg];
        const float4 dca = reinterpret_cast<const float4*>(decay)[r0 * 4 + mg];
        const float4 dpb = reinterpret_cast<const float4*>(damp)[(r0 + 1) * 4 + mg];
        const float4 dcb = reinterpret_cast<const float4*>(decay)[(r0 + 1) * 4 + mg];
        q2[4*mg+0] = (v2f){1.f - sigmoid_fast(dpa.x) * sigmoid_fast(dca.x),
                           1.f - sigmoid_fast(dpb.x) * sigmoid_fast(dcb.x)};
        q2[4*mg+1] = (v2f){1.f - sigmoid_fast(dpa.y) * sigmoid_fast(dca.y),
                           1.f - sigmoid_fast(dpb.y) * sigmoid_fast(dcb.y)};
        q2[4*mg+2] = (v2f){1.f - sigmoid_fast(dpa.z) * sigmoid_fast(dca.z),
                           1.f - sigmoid_fast(dpb.z) * sigmoid_fast(dcb.z)};
        q2[4*mg+3] = (v2f){1.f - sigmoid_fast(dpa.w) * sigmoid_fast(dca.w),
                           1.f - sigmoid_fast(dpb.w) * sigmoid_fast(dcb.w)};
    }
}

// Channel-packed q2[16] and c2[16] (= p * ema * proj / sqrt(ND)) for rows r0,r0+1.
__device__ __forceinline__ void load_qc2p(const float* __restrict__ damp,
                                          const float* __restrict__ decay,
                                          const float* __restrict__ ema,
                                          const float* __restrict__ proj,
                                          int r0, v2f* q2, v2f* c2) {
#pragma unroll
    for (int mg = 0; mg < 4; ++mg) {
        const float4 dpa = reinterpret_cast<const float4*>(damp)[r0 * 4 + mg];
        const float4 dca = reinterpret_cast<const float4*>(decay)[r0 * 4 + mg];
        const float4 ema4a = reinterpret_cast<const float4*>(ema)[r0 * 4 + mg];
        const float4 pja = reinterpret_cast<const float4*>(proj)[r0 * 4 + mg];
        const float4 dpb = reinterpret_cast<const float4*>(damp)[(r0 + 1) * 4 + mg];
        const float4 dcb = reinterpret_cast<const float4*>(decay)[(r0 + 1) * 4 + mg];
        const float4 ema4b = reinterpret_cast<const float4*>(ema)[(r0 + 1) * 4 + mg];
        const float4 pjb = reinterpret_cast<const float4*>(proj)[(r0 + 1) * 4 + mg];
        const float pa0 = sigmoid_fast(dpa.x), pa1 = sigmoid_fast(dpa.y),
                    pa2 = sigmoid_fast(dpa.z), pa3 = sigmoid_fast(dpa.w);
        const float pb0 = sigmoid_fast(dpb.x), pb1 = sigmoid_fast(dpb.y),
                    pb2 = sigmoid_fast(dpb.z), pb3 = sigmoid_fast(dpb.w);
        q2[4*mg+0] = (v2f){1.f - pa0 * sigmoid_fast(dca.x), 1.f - pb0 * sigmoid_fast(dcb.x)};
        q2[4*mg+1] = (v2f){1.f - pa1 * sigmoid_fast(dca.y), 1.f - pb1 * sigmoid_fast(dcb.y)};
        q2[4*mg+2] = (v2f){1.f - pa2 * sigmoid_fast(dca.z), 1.f - pb2 * sigmoid_fast(dcb.z)};
        q2[4*mg+3] = (v2f){1.f - pa3 * sigmoid_fast(dca.w), 1.f - pb3 * sigmoid_fast(dcb.w)};
        c2[4*mg+0] = (v2f){pa0 * ema4a.x * pja.x * 0.25f, pb0 * ema4b.x * pjb.x * 0.25f};
        c2[4*mg+1] = (v2f){pa1 * ema4a.y * pja.y * 0.25f, pb1 * ema4b.y * pjb.y * 0.25f};
        c2[4*mg+2] = (v2f){pa2 * ema4a.z * pja.z * 0.25f, pb2 * ema4b.z * pjb.z * 0.25f};
        c2[4*mg+3] = (v2f){pa3 * ema4a.w * pja.w * 0.25f, pb3 * ema4b.w * pjb.w * 0.25f};
    }
}

// ---------------- Phase A: per-chunk local states (both directions) ----------
// Block = 128 threads / 128 channels (2 per lane, float2 loads = 512B/wave-req).
// Wave 0 fwd (u = i), wave 1 bwd (u = i ^ 63). 4-buffer x 8-j rotated pipeline
// (32 loads in flight), fully flattened -> static indexing, bounded liveness.
__global__ __launch_bounds__(128, 2) void ema_summary_kernel(
    const float* __restrict__ x, const float* __restrict__ damp,
    const float* __restrict__ decay, const int* __restrict__ mask,
    float* __restrict__ fwdS, float* __restrict__ bwdS)
{
    __shared__ float smask[CK];
    const int lane = threadIdx.x & 63;
    const int wid  = threadIdx.x >> 6;          // 0 = fwd, 1 = bwd
    const int d0 = blockIdx.x * 128 + lane * 2;
    const int b  = blockIdx.y;
    const int ch = blockIdx.z;
    const int j0 = ch * CK;
    const int um = wid ? (CK - 1) : 0;          // u = i ^ um

    const float* xp = x + (size_t)j0 * BD + (size_t)b * D + d0;
    const int*   mp = mask + (size_t)b * L + j0;
    if (threadIdx.x < CK) smask[threadIdx.x] = (float)mp[threadIdx.x];
    __syncthreads();

    const int r0 = wid ? (d0 + D) : d0;
    v2f q2[16], st2[16];
    load_q2p(damp, decay, r0, q2);
#pragma unroll
    for (int k = 0; k < 16; ++k) st2[k] = (v2f){0.f, 0.f};

    v2f xA[8], xB[8], xC[8], xD[8];

#define SLOADG(XR, G) \
    _Pragma("unroll") \
    for (int v = 0; v < 8; ++v) { \
        const int u = ((G) + v) ^ um; \
        XR[v] = *reinterpret_cast<const v2f*>(xp + (size_t)u * BD); \
    }
#define SCOMPG(XR, G) \
    _Pragma("unroll") \
    for (int v = 0; v < 8; ++v) { \
        const int u = ((G) + v) ^ um; \
        const float m = smask[u]; \
        const v2f xm2 = XR[v] * (v2f){m, m}; \
        _Pragma("unroll") \
        for (int k = 0; k < 16; ++k) st2[k] = q2[k] * st2[k] + xm2; \
    }

    SLOADG(xA, 0)
    SLOADG(xB, 8)
    SLOADG(xC, 16)
    SLOADG(xD, 24)
    SCOMPG(xA, 0)  SLOADG(xA, 32)
    SCOMPG(xB, 8)  SLOADG(xB, 40)
    SCOMPG(xC, 16) SLOADG(xC, 48)
    SCOMPG(xD, 24) SLOADG(xD, 56)
    SCOMPG(xA, 32)
    SCOMPG(xB, 40)
    SCOMPG(xC, 48)
    SCOMPG(xD, 56)
#undef SLOADG
#undef SCOMPG

    float* Sx = wid ? bwdS : fwdS;
    float4* s4 = reinterpret_cast<float4*>(Sx) + ((size_t)(b * NC + ch) * D + d0) * 4;
#pragma unroll
    for (int mg = 0; mg < 4; ++mg) {
        s4[mg]     = make_float4(st2[4*mg+0].x, st2[4*mg+1].x, st2[4*mg+2].x, st2[4*mg+3].x);
        s4[4 + mg] = make_float4(st2[4*mg+0].y, st2[4*mg+1].y, st2[4*mg+2].y, st2[4*mg+3].y);
    }
}

// ---------------- Phase B: prefix across chunks (in-place -> entry states) ---
// One thread per (b, d, mode). All chunk values prefetched, then the two
// serial fma chains (fwd + bwd) interleaved for 2x chain ILP.
__global__ __launch_bounds__(256) void ema_prefix_kernel(
    const float* __restrict__ damp, const float* __restrict__ decay,
    float* __restrict__ fwdS, float* __restrict__ bwdS)
{
    const int tid = blockIdx.x * 256 + threadIdx.x;
    const int m = tid & (ND - 1);
    const int d = (tid >> 4) & (D - 1);
    const int b = tid >> 14;
    const size_t CS = (size_t)D * ND;   // stride between chunks
    const size_t off = (size_t)b * NC * CS + (size_t)d * ND + m;
    float* fb = fwdS + off;
    float* bb = bwdS + off;

    const int idxf = d * ND + m;
    const int idxb = (d + D) * ND + m;
    float qf = 1.f - sigmoid_fast(damp[idxf]) * sigmoid_fast(decay[idxf]);
    float qb = 1.f - sigmoid_fast(damp[idxb]) * sigmoid_fast(decay[idxb]);
#pragma unroll
    for (int s = 0; s < 6; ++s) { qf *= qf; qb *= qb; }   // q^64

    float Ef[NC], Eb[NC];
#pragma unroll
    for (int i = 0; i < NC; ++i) Ef[i] = fb[(size_t)i * CS];
#pragma unroll
    for (int i = 0; i < NC; ++i) Eb[i] = bb[(size_t)i * CS];

    float F = 0.f, G = 0.f;
#pragma unroll
    for (int i = 0; i < NC; ++i) {
        fb[(size_t)i * CS] = F;               F = fmaf(qf, F, Ef[i]);
        bb[(size_t)(NC-1-i) * CS] = G;        G = fmaf(qb, G, Eb[NC-1-i]);
    }
}

// ---------------- Phase C: apply (both directions + residual + silu) ---------
// 2 channels/lane (float2), channel-packed pk math: 16 pk state-fma + 16 pk
// dot-fma per step cover BOTH channels. Half-LDS fwd/bwd exchange (float2,
// 32KB); 4-buffer x 8-j rotated prefetch pipeline, fully flattened.
__global__ __launch_bounds__(128, 2) void ema_apply_kernel(
    const float* __restrict__ x, const float* __restrict__ damp,
    const float* __restrict__ decay, const float* __restrict__ ema,
    const float* __restrict__ proj, const float* __restrict__ rw,
    const int* __restrict__ mask,
    const float* __restrict__ fwdS, const float* __restrict__ bwdS,
    float* __restrict__ out)
{
    constexpr int HALF = CK / 2;
    __shared__ v2f hacc[2][HALF][64];        // 32 KB
    __shared__ float smask[CK];

    const int lane = threadIdx.x & 63;
    const int wid  = threadIdx.x >> 6;       // 0 = fwd, 1 = bwd
    const int d0 = blockIdx.x * 128 + lane * 2;
    const int b  = blockIdx.y;
    const int ch = blockIdx.z;
    const int j0 = ch * CK;
    const int um = wid ? (CK - 1) : 0;       // u = i ^ um

    const float* xp = x   + (size_t)j0 * BD + (size_t)b * D + d0;
    float*       op = out + (size_t)j0 * BD + (size_t)b * D + d0;
    const int*   mp = mask + (size_t)b * L + j0;
    if (threadIdx.x < CK) smask[threadIdx.x] = (float)mp[threadIdx.x];

    const int r0 = wid ? (d0 + D) : d0;
    const v2f weff2 = wid ? (v2f){0.f, 0.f} : (v2f){rw[d0], rw[d0 + 1]};
    const float* Sx = wid ? bwdS : fwdS;

    v2f q2[16], c2[16], st2[16];
    load_qc2p(damp, decay, ema, proj, r0, q2, c2);
    {
        const float4* s4 = reinterpret_cast<const float4*>(Sx) + ((size_t)(b * NC + ch) * D + d0) * 4;
#pragma unroll
        for (int mg = 0; mg < 4; ++mg) {
            const float4 va = s4[mg];
            const float4 vb = s4[4 + mg];
            st2[4*mg+0] = (v2f){va.x, vb.x};
            st2[4*mg+1] = (v2f){va.y, vb.y};
            st2[4*mg+2] = (v2f){va.z, vb.z};
            st2[4*mg+3] = (v2f){va.w, vb.w};
        }
    }
    __syncthreads();   // smask visible

    v2f xA[8], xB[8], xC[8], xD[8];

#define ALOADG(XR, G) \
    _Pragma("unroll") \
    for (int v = 0; v < 8; ++v) { \
        const int u = ((G) + v) ^ um; \
        XR[v] = *reinterpret_cast<const v2f*>(xp + (size_t)u * BD); \
    }
#define ASTEP(XR, V, G) \
    const int u = ((G) + (V)) ^ um; \
    const v2f xraw2 = XR[V]; \
    const float m = smask[u]; \
    const v2f xm2 = xraw2 * (v2f){m, m}; \
    _Pragma("unroll") \
    for (int k = 0; k < 16; ++k) st2[k] = q2[k] * st2[k] + xm2; \
    v2f a0 = c2[0] * st2[0], a1 = c2[1] * st2[1], \
        a2 = c2[2] * st2[2], a3 = c2[3] * st2[3]; \
    _Pragma("unroll") \
    for (int k = 4; k < 16; k += 4) { \
        a0 = c2[k+0] * st2[k+0] + a0; \
        a1 = c2[k+1] * st2[k+1] + a1; \
        a2 = c2[k+2] * st2[k+2] + a2; \
        a3 = c2[k+3] * st2[k+3] + a3; \
    } \
    const v2f sres = (a0 + a1) + (a2 + a3);
#define ACOMP_LDS(XR, G) \
    _Pragma("unroll") \
    for (int v = 0; v < 8; ++v) { \
        ASTEP(XR, v, G) \
        hacc[wid][u & (HALF - 1)][lane] = xraw2 * weff2 + sres; \
    }
#define ACOMP_OUT(XR, G) \
    _Pragma("unroll") \
    for (int v = 0; v < 8; ++v) { \
        ASTEP(XR, v, G) \
        const v2f tv  = xraw2 * weff2 + sres; \
        const v2f val = tv + hacc[ow][u & (HALF - 1)][lane]; \
        v2f o; \
        o.x = val.x * __builtin_amdgcn_rcpf(1.0f + __expf(-val.x)); \
        o.y = val.y * __builtin_amdgcn_rcpf(1.0f + __expf(-val.y)); \
        *reinterpret_cast<v2f*>(op + (size_t)u * BD) = o; \
    }

    // phase 1 (scan steps 0..31 -> LDS), phase-2 loads issued before barrier
    ALOADG(xA, 0)
    ALOADG(xB, 8)
    ALOADG(xC, 16)
    ALOADG(xD, 24)
    ACOMP_LDS(xA, 0)  ALOADG(xA, 32)
    ACOMP_LDS(xB, 8)  ALOADG(xB, 40)
    ACOMP_LDS(xC, 16) ALOADG(xC, 48)
    ACOMP_LDS(xD, 24) ALOADG(xD, 56)
    __syncthreads();

    // phase 2 (scan steps 32..63): combine with other wave's half, silu, store
    const int ow = 1 - wid;
    ACOMP_OUT(xA, 32)
    ACOMP_OUT(xB, 40)
    ACOMP_OUT(xC, 48)
    ACOMP_OUT(xD, 56)
#undef ALOADG
#undef ASTEP
#undef ACOMP_LDS
#undef ACOMP_OUT
}

// ---------------- Fallback: validated single-pass scans ----------------------
template<int DIR>
__device__ __forceinline__ void ema_scan_body(
    const float* __restrict__ x, const float* __restrict__ damp,
    const float* __restrict__ decay, const float* __restrict__ ema,
    const float* __restrict__ proj, const float* __restrict__ rw,
    const int* __restrict__ mask, float* __restrict__ out)
{
    const int t  = threadIdx.x;
    const int ng = t & 3;
    const int dl = t >> 2;
    const int d  = blockIdx.x * 16 + dl;
    const int b  = blockIdx.y;
    const int row = (DIR == 0) ? d : (d + D);

    float q[4], c[4];
#pragma unroll
    for (int k = 0; k < 4; ++k) {
        const int idx = row * ND + ng * 4 + k;
        const float p  = sigmoid_precise(damp[idx]);
        const float sd = sigmoid_precise(decay[idx]);
        q[k] = 1.0f - p * sd;
        c[k] = p * ema[idx] * proj[idx] * 0.25f;
    }
    const float w = rw[d];
    const float* xp = x + (size_t)b * D + d;
    float*       op = out + (size_t)b * D + d;
    const int*   mp = mask + (size_t)b * L;
    float s0 = 0.f, s1 = 0.f, s2 = 0.f, s3 = 0.f;

    for (int jj = 0; jj < L; jj += 4) {
        float xv[4], mf[4];
#pragma unroll
        for (int u = 0; u < 4; ++u) {
            const int j = (DIR == 0) ? (jj + u) : (L - 1 - (jj + u));
            xv[u] = xp[(size_t)j * BD];
            mf[u] = (float)mp[j];
        }
        float acc[4];
#pragma unroll
        for (int u = 0; u < 4; ++u) {
            const float xm = xv[u] * mf[u];
            s0 = fmaf(q[0], s0, xm);
            s1 = fmaf(q[1], s1, xm);
            s2 = fmaf(q[2], s2, xm);
            s3 = fmaf(q[3], s3, xm);
            acc[u] = fmaf(c[1], s1, c[0] * s0) + fmaf(c[3], s3, c[2] * s2);
        }
#pragma unroll
        for (int u = 0; u < 4; ++u) acc[u] += __shfl_xor(acc[u], 1);
#pragma unroll
        for (int u = 0; u < 4; ++u) acc[u] += __shfl_xor(acc[u], 2);
        if (ng == 0) {
#pragma unroll
            for (int u = 0; u < 4; ++u) {
                const int j = (DIR == 0) ? (jj + u) : (L - 1 - (jj + u));
                const size_t oi = (size_t)j * BD;
                if (DIR == 0) op[oi] = fmaf(xv[u], w, acc[u]);
                else { const float v = op[oi] + acc[u]; op[oi] = v / (1.0f + expf(-v)); }
            }
        }
    }
}

__global__ __launch_bounds__(64) void ema_fwd_kernel(
    const float* __restrict__ x, const float* __restrict__ damp,
    const float* __restrict__ decay, const float* __restrict__ ema,
    const float* __restrict__ proj, const float* __restrict__ rw,
    const int* __restrict__ mask, float* __restrict__ out)
{ ema_scan_body<0>(x, damp, decay, ema, proj, rw, mask, out); }

__global__ __launch_bounds__(64) void ema_bwd_kernel(
    const float* __restrict__ x, const float* __restrict__ damp,
    const float* __restrict__ decay, const float* __restrict__ ema,
    const float* __restrict__ proj, const float* __restrict__ rw,
    const int* __restrict__ mask, float* __restrict__ out)
{ ema_scan_body<1>(x, damp, decay, ema, proj, rw, mask, out); }

// ---------------- driver -----------------------------------------------------
extern "C" void kernel_launch(void* const* d_in, const int* in_sizes, int n_in,
                              void* d_out, int out_size, void* d_ws, size_t ws_size,
                              hipStream_t stream) {
    (void)in_sizes; (void)n_in; (void)out_size;
    const float* x     = (const float*)d_in[0];
    const float* damp  = (const float*)d_in[1];
    const float* decay = (const float*)d_in[2];
    const float* ema   = (const float*)d_in[3];
    const float* proj  = (const float*)d_in[4];
    const float* rw    = (const float*)d_in[5];
    const int*   mask  = (const int*)d_in[6];
    float* out = (float*)d_out;

    const size_t need = (size_t)2 * B * NC * D * ND * sizeof(float);  // 33.6 MB

    if (ws_size >= need) {
        float* fwdS = (float*)d_ws;
        float* bwdS = fwdS + (size_t)B * NC * D * ND;
        dim3 g(D / 128, B, NC);
        ema_summary_kernel<<<g, dim3(128), 0, stream>>>(x, damp, decay, mask, fwdS, bwdS);
        ema_prefix_kernel<<<dim3((B * D * ND) / 256), dim3(256), 0, stream>>>(damp, decay, fwdS, bwdS);
        ema_apply_kernel<<<g, dim3(128), 0, stream>>>(x, damp, decay, ema, proj, rw, mask,
                                                      fwdS, bwdS, out);
    } else {
        dim3 grid(D / 16, B);
        dim3 block(64);
        ema_fwd_kernel<<<grid, block, 0, stream>>>(x, damp, decay, ema, proj, rw, mask, out);
        ema_bwd_kernel<<<grid, block, 0, stream>>>(x, damp, decay, ema, proj, rw, mask, out);
    }
}

// Round 11
// 183.958 us; speedup vs baseline: 1.1000x; 1.1000x over previous
//
#include <hip/hip_runtime.h>
#include <math.h>

#define L 2048
#define B 8
#define D 1024
#define ND 16
#define BD (B*D)
#define CK 128               // chunk length
#define NC (L/CK)            // 16 chunks

typedef float v2f __attribute__((ext_vector_type(2)));

__device__ __forceinline__ float sigmoid_precise(float v) {
    return 1.0f / (1.0f + expf(-v));
}
// fast sigmoid: v_exp + v_rcp (~3e-7 rel err; tolerance is 0.0625 abs)
__device__ __forceinline__ float sigmoid_fast(float v) {
    return __builtin_amdgcn_rcpf(1.0f + __expf(-v));
}

// Per-mode decay packed as 8 x float2 (modes 2i,2i+1 in lanes .x/.y).
__device__ __forceinline__ void load_q2(const float* __restrict__ damp,
                                        const float* __restrict__ decay,
                                        int row, v2f* q2) {
#pragma unroll
    for (int mg = 0; mg < 4; ++mg) {
        const float4 dp = reinterpret_cast<const float4*>(damp)[row * 4 + mg];
        const float4 dc = reinterpret_cast<const float4*>(decay)[row * 4 + mg];
        const float qa = 1.f - sigmoid_fast(dp.x) * sigmoid_fast(dc.x);
        const float qb = 1.f - sigmoid_fast(dp.y) * sigmoid_fast(dc.y);
        const float qc = 1.f - sigmoid_fast(dp.z) * sigmoid_fast(dc.z);
        const float qd = 1.f - sigmoid_fast(dp.w) * sigmoid_fast(dc.w);
        q2[2*mg+0] = (v2f){qa, qb};
        q2[2*mg+1] = (v2f){qc, qd};
    }
}

// Packed decay q2[8] and output coefficient c2[8] (= p * ema * proj / sqrt(ND)).
__device__ __forceinline__ void load_qc2(const float* __restrict__ damp,
                                         const float* __restrict__ decay,
                                         const float* __restrict__ ema,
                                         const float* __restrict__ proj,
                                         int row, v2f* q2, v2f* c2) {
#pragma unroll
    for (int mg = 0; mg < 4; ++mg) {
        const float4 dp = reinterpret_cast<const float4*>(damp)[row * 4 + mg];
        const float4 dc = reinterpret_cast<const float4*>(decay)[row * 4 + mg];
        const float4 em = reinterpret_cast<const float4*>(ema)[row * 4 + mg];
        const float4 pj = reinterpret_cast<const float4*>(proj)[row * 4 + mg];
        const float p0 = sigmoid_fast(dp.x), p1 = sigmoid_fast(dp.y),
                    p2 = sigmoid_fast(dp.z), p3 = sigmoid_fast(dp.w);
        q2[2*mg+0] = (v2f){1.f - p0 * sigmoid_fast(dc.x), 1.f - p1 * sigmoid_fast(dc.y)};
        q2[2*mg+1] = (v2f){1.f - p2 * sigmoid_fast(dc.z), 1.f - p3 * sigmoid_fast(dc.w)};
        c2[2*mg+0] = (v2f){p0 * em.x * pj.x * 0.25f, p1 * em.y * pj.y * 0.25f};
        c2[2*mg+1] = (v2f){p2 * em.z * pj.z * 0.25f, p3 * em.w * pj.w * 0.25f};
    }
}

// ---------------- Phase A: per-chunk local states (both directions) ----------
// Block = 128 threads: wave 0 scans forward (u = i), wave 1 backward
// (u = i ^ (CK-1)). Software-pipelined 3-buffer prefetch (fully flattened,
// static register indexing only -> same ~100 VGPR profile as the proven r9).
// Masks staged to LDS once per block. Packed float2 mode math (v_pk_fma_f32).
__global__ __launch_bounds__(128, 2) void ema_summary_kernel(
    const float* __restrict__ x, const float* __restrict__ damp,
    const float* __restrict__ decay, const int* __restrict__ mask,
    float* __restrict__ fwdS, float* __restrict__ bwdS)
{
    __shared__ float smask[CK];
    const int lane = threadIdx.x & 63;
    const int wid  = threadIdx.x >> 6;          // 0 = fwd, 1 = bwd
    const int d  = blockIdx.x * 64 + lane;
    const int b  = blockIdx.y;
    const int ch = blockIdx.z;
    const int j0 = ch * CK;
    const int um = wid ? (CK - 1) : 0;          // u = i ^ um

    const float* xp = x + (size_t)j0 * BD + (size_t)b * D + d;
    const int*   mp = mask + (size_t)b * L + j0;
    if (threadIdx.x < CK) smask[threadIdx.x] = (float)mp[threadIdx.x];
    __syncthreads();

    const int row = wid ? (d + D) : d;
    v2f q2[8], st2[8];
    load_q2(damp, decay, row, q2);
#pragma unroll
    for (int k = 0; k < 8; ++k) st2[k] = (v2f){0.f, 0.f};

    float xA[16], xB[16], xC[16];

#define SLOADG(XR, G) \
    _Pragma("unroll") \
    for (int v = 0; v < 16; ++v) { \
        const int u = ((G) + v) ^ um; \
        XR[v] = xp[(size_t)u * BD]; \
    }
#define SCOMPG(XR, G) \
    _Pragma("unroll") \
    for (int v = 0; v < 16; ++v) { \
        const int u = ((G) + v) ^ um; \
        const float xm = XR[v] * smask[u]; \
        const v2f xm2 = {xm, xm}; \
        _Pragma("unroll") \
        for (int k = 0; k < 8; ++k) st2[k] = q2[k] * st2[k] + xm2; \
    }

    SLOADG(xA, 0)
    SLOADG(xB, 16)
    SLOADG(xC, 32)
    SCOMPG(xA, 0)   SLOADG(xA, 48)
    SCOMPG(xB, 16)  SLOADG(xB, 64)
    SCOMPG(xC, 32)  SLOADG(xC, 80)
    SCOMPG(xA, 48)  SLOADG(xA, 96)
    SCOMPG(xB, 64)  SLOADG(xB, 112)
    SCOMPG(xC, 80)
    SCOMPG(xA, 96)
    SCOMPG(xB, 112)
#undef SLOADG
#undef SCOMPG

    float* Sx = wid ? bwdS : fwdS;
    float4* s4 = reinterpret_cast<float4*>(Sx) + ((size_t)(b * NC + ch) * D + d) * 4;
#pragma unroll
    for (int mg = 0; mg < 4; ++mg)
        s4[mg] = make_float4(st2[2*mg+0].x, st2[2*mg+0].y, st2[2*mg+1].x, st2[2*mg+1].y);
}

// ---------------- Phase B: prefix across chunks (in-place -> entry states) ---
// One thread per (b, d, mode); 1024-thread blocks -> 4 KB contiguous segments
// per chunk index (was 1 KB). All NC chunk values prefetched, then the two
// serial fma chains (fwd + bwd) interleaved for 2x chain ILP.
__global__ __launch_bounds__(1024) void ema_prefix_kernel(
    const float* __restrict__ damp, const float* __restrict__ decay,
    float* __restrict__ fwdS, float* __restrict__ bwdS)
{
    const int tid = blockIdx.x * 1024 + threadIdx.x;
    const int m = tid & (ND - 1);
    const int d = (tid >> 4) & (D - 1);
    const int b = tid >> 14;
    const size_t CS = (size_t)D * ND;   // stride between chunks
    const size_t off = (size_t)b * NC * CS + (size_t)d * ND + m;
    float* fb = fwdS + off;
    float* bb = bwdS + off;

    const int idxf = d * ND + m;
    const int idxb = (d + D) * ND + m;
    float qf = 1.f - sigmoid_fast(damp[idxf]) * sigmoid_fast(decay[idxf]);
    float qb = 1.f - sigmoid_fast(damp[idxb]) * sigmoid_fast(decay[idxb]);
#pragma unroll
    for (int s = 0; s < 7; ++s) { qf *= qf; qb *= qb; }   // q^128

    float Ef[NC], Eb[NC];
#pragma unroll
    for (int i = 0; i < NC; ++i) Ef[i] = fb[(size_t)i * CS];
#pragma unroll
    for (int i = 0; i < NC; ++i) Eb[i] = bb[(size_t)i * CS];

    float F = 0.f, G = 0.f;
#pragma unroll
    for (int i = 0; i < NC; ++i) {
        fb[(size_t)i * CS] = F;               F = fmaf(qf, F, Ef[i]);
        bb[(size_t)(NC-1-i) * CS] = G;        G = fmaf(qb, G, Eb[NC-1-i]);
    }
}

// ---------------- Phase C: apply (both directions + residual + silu) ---------
// r9 structure at CK=128: half-LDS mirror exchange (hacc[2][64][64], 32 KB) +
// 3-buffer flattened prefetch pipeline. Wave 0 causal (u=i), wave 1
// anti-causal (u=i^127). Phase 1 = scan steps 0..63 -> own LDS half; one
// barrier; phase 2 = steps 64..127 combined with the other wave's half.
__global__ __launch_bounds__(128, 2) void ema_apply_kernel(
    const float* __restrict__ x, const float* __restrict__ damp,
    const float* __restrict__ decay, const float* __restrict__ ema,
    const float* __restrict__ proj, const float* __restrict__ rw,
    const int* __restrict__ mask,
    const float* __restrict__ fwdS, const float* __restrict__ bwdS,
    float* __restrict__ out)
{
    constexpr int HALF = CK / 2;
    __shared__ float hacc[2][HALF][64];      // 32 KB
    __shared__ float smask[CK];

    const int lane = threadIdx.x & 63;
    const int wid  = threadIdx.x >> 6;       // 0 = fwd, 1 = bwd
    const int d  = blockIdx.x * 64 + lane;
    const int b  = blockIdx.y;
    const int ch = blockIdx.z;
    const int j0 = ch * CK;
    const int um = wid ? (CK - 1) : 0;       // u = i ^ um

    const float* xp = x   + (size_t)j0 * BD + (size_t)b * D + d;
    float*       op = out + (size_t)j0 * BD + (size_t)b * D + d;
    const int*   mp = mask + (size_t)b * L + j0;
    if (threadIdx.x < CK) smask[threadIdx.x] = (float)mp[threadIdx.x];

    const int    row  = wid ? (d + D) : d;
    const float  weff = wid ? 0.f : rw[d];           // residual only on fwd wave
    const float* Sx   = wid ? bwdS : fwdS;

    v2f q2[8], c2[8], st2[8];
    load_qc2(damp, decay, ema, proj, row, q2, c2);
    {
        const float4* s4 = reinterpret_cast<const float4*>(Sx) + ((size_t)(b * NC + ch) * D + d) * 4;
#pragma unroll
        for (int mg = 0; mg < 4; ++mg) {
            const float4 v = s4[mg];
            st2[2*mg+0] = (v2f){v.x, v.y};
            st2[2*mg+1] = (v2f){v.z, v.w};
        }
    }
    __syncthreads();   // smask visible

    float xA[16], xB[16], xC[16];

#define ALOADG(XR, G) \
    _Pragma("unroll") \
    for (int v = 0; v < 16; ++v) { \
        const int u = ((G) + v) ^ um; \
        XR[v] = xp[(size_t)u * BD]; \
    }
#define ASTEP(XR, V, G) \
    const int u = ((G) + (V)) ^ um; \
    const float xraw = XR[V]; \
    const float xm   = xraw * smask[u]; \
    const v2f xm2 = {xm, xm}; \
    _Pragma("unroll") \
    for (int k = 0; k < 8; ++k) st2[k] = q2[k] * st2[k] + xm2; \
    v2f a0 = c2[0] * st2[0], a1 = c2[1] * st2[1], \
        a2 = c2[2] * st2[2], a3 = c2[3] * st2[3]; \
    a0 = c2[4] * st2[4] + a0; \
    a1 = c2[5] * st2[5] + a1; \
    a2 = c2[6] * st2[6] + a2; \
    a3 = c2[7] * st2[7] + a3; \
    const v2f sres = (a0 + a1) + (a2 + a3);
#define ACOMP_LDS(XR, G) \
    _Pragma("unroll") \
    for (int v = 0; v < 16; ++v) { \
        ASTEP(XR, v, G) \
        hacc[wid][u & (HALF - 1)][lane] = fmaf(xraw, weff, sres.x + sres.y); \
    }
#define ACOMP_OUT(XR, G) \
    _Pragma("unroll") \
    for (int v = 0; v < 16; ++v) { \
        ASTEP(XR, v, G) \
        const float tv  = fmaf(xraw, weff, sres.x + sres.y); \
        const float val = tv + hacc[ow][u & (HALF - 1)][lane]; \
        op[(size_t)u * BD] = val * __builtin_amdgcn_rcpf(1.0f + __expf(-val)); \
    }

    // phase 1 (scan steps 0..63 -> own LDS half), later loads kept in flight
    ALOADG(xA, 0)
    ALOADG(xB, 16)
    ALOADG(xC, 32)
    ACOMP_LDS(xA, 0)   ALOADG(xA, 48)
    ACOMP_LDS(xB, 16)  ALOADG(xB, 64)
    ACOMP_LDS(xC, 32)  ALOADG(xC, 80)
    ACOMP_LDS(xA, 48)  ALOADG(xA, 96)
    __syncthreads();

    // phase 2 (scan steps 64..127): combine with other wave's half, silu, store
    const int ow = 1 - wid;
    ACOMP_OUT(xB, 64)  ALOADG(xB, 112)
    ACOMP_OUT(xC, 80)
    ACOMP_OUT(xA, 96)
    ACOMP_OUT(xB, 112)
#undef ALOADG
#undef ASTEP
#undef ACOMP_LDS
#undef ACOMP_OUT
}

// ---------------- Fallback: validated single-pass scans ----------------------
template<int DIR>
__device__ __forceinline__ void ema_scan_body(
    const float* __restrict__ x, const float* __restrict__ damp,
    const float* __restrict__ decay, const float* __restrict__ ema,
    const float* __restrict__ proj, const float* __restrict__ rw,
    const int* __restrict__ mask, float* __restrict__ out)
{
    const int t  = threadIdx.x;
    const int ng = t & 3;
    const int dl = t >> 2;
    const int d  = blockIdx.x * 16 + dl;
    const int b  = blockIdx.y;
    const int row = (DIR == 0) ? d : (d + D);

    float q[4], c[4];
#pragma unroll
    for (int k = 0; k < 4; ++k) {
        const int idx = row * ND + ng * 4 + k;
        const float p  = sigmoid_precise(damp[idx]);
        const float sd = sigmoid_precise(decay[idx]);
        q[k] = 1.0f - p * sd;
        c[k] = p * ema[idx] * proj[idx] * 0.25f;
    }
    const float w = rw[d];
    const float* xp = x + (size_t)b * D + d;
    float*       op = out + (size_t)b * D + d;
    const int*   mp = mask + (size_t)b * L;
    float s0 = 0.f, s1 = 0.f, s2 = 0.f, s3 = 0.f;

    for (int jj = 0; jj < L; jj += 4) {
        float xv[4], mf[4];
#pragma unroll
        for (int u = 0; u < 4; ++u) {
            const int j = (DIR == 0) ? (jj + u) : (L - 1 - (jj + u));
            xv[u] = xp[(size_t)j * BD];
            mf[u] = (float)mp[j];
        }
        float acc[4];
#pragma unroll
        for (int u = 0; u < 4; ++u) {
            const float xm = xv[u] * mf[u];
            s0 = fmaf(q[0], s0, xm);
            s1 = fmaf(q[1], s1, xm);
            s2 = fmaf(q[2], s2, xm);
            s3 = fmaf(q[3], s3, xm);
            acc[u] = fmaf(c[1], s1, c[0] * s0) + fmaf(c[3], s3, c[2] * s2);
        }
#pragma unroll
        for (int u = 0; u < 4; ++u) acc[u] += __shfl_xor(acc[u], 1);
#pragma unroll
        for (int u = 0; u < 4; ++u) acc[u] += __shfl_xor(acc[u], 2);
        if (ng == 0) {
#pragma unroll
            for (int u = 0; u < 4; ++u) {
                const int j = (DIR == 0) ? (jj + u) : (L - 1 - (jj + u));
                const size_t oi = (size_t)j * BD;
                if (DIR == 0) op[oi] = fmaf(xv[u], w, acc[u]);
                else { const float v = op[oi] + acc[u]; op[oi] = v / (1.0f + expf(-v)); }
            }
        }
    }
}

__global__ __launch_bounds__(64) void ema_fwd_kernel(
    const float* __restrict__ x, const float* __restrict__ damp,
    const float* __restrict__ decay, const float* __restrict__ ema,
    const float* __restrict__ proj, const float* __restrict__ rw,
    const int* __restrict__ mask, float* __restrict__ out)
{ ema_scan_body<0>(x, damp, decay, ema, proj, rw, mask, out); }

__global__ __launch_bounds__(64) void ema_bwd_kernel(
    const float* __restrict__ x, const float* __restrict__ damp,
    const float* __restrict__ decay, const float* __restrict__ ema,
    const float* __restrict__ proj, const float* __restrict__ rw,
    const int* __restrict__ mask, float* __restrict__ out)
{ ema_scan_body<1>(x, damp, decay, ema, proj, rw, mask, out); }

// ---------------- driver -----------------------------------------------------
extern "C" void kernel_launch(void* const* d_in, const int* in_sizes, int n_in,
                              void* d_out, int out_size, void* d_ws, size_t ws_size,
                              hipStream_t stream) {
    (void)in_sizes; (void)n_in; (void)out_size;
    const float* x     = (const float*)d_in[0];
    const float* damp  = (const float*)d_in[1];
    const float* decay = (const float*)d_in[2];
    const float* ema   = (const float*)d_in[3];
    const float* proj  = (const float*)d_in[4];
    const float* rw    = (const float*)d_in[5];
    const int*   mask  = (const int*)d_in[6];
    float* out = (float*)d_out;

    const size_t need = (size_t)2 * B * NC * D * ND * sizeof(float);  // 16.8 MB

    if (ws_size >= need) {
        float* fwdS = (float*)d_ws;
        float* bwdS = fwdS + (size_t)B * NC * D * ND;
        dim3 g(D / 64, B, NC);
        ema_summary_kernel<<<g, dim3(128), 0, stream>>>(x, damp, decay, mask, fwdS, bwdS);
        ema_prefix_kernel<<<dim3((B * D * ND) / 1024), dim3(1024), 0, stream>>>(damp, decay, fwdS, bwdS);
        ema_apply_kernel<<<g, dim3(128), 0, stream>>>(x, damp, decay, ema, proj, rw, mask,
                                                      fwdS, bwdS, out);
    } else {
        dim3 grid(D / 16, B);
        dim3 block(64);
        ema_fwd_kernel<<<grid, block, 0, stream>>>(x, damp, decay, ema, proj, rw, mask, out);
        ema_bwd_kernel<<<grid, block, 0, stream>>>(x, damp, decay, ema, proj, rw, mask, out);
    }
}